// Round 14
// baseline (245.016 us; speedup 1.0000x reference)
//
#include <hip/hip_runtime.h>
#include <hip/hip_bf16.h>

// LocalAttention: B=8, S=4096, D=512, H=8, hd=64, WINDOW=5, STRIDE=4, nw=1024
// Pipeline (4 launches): cvt_fused (x->bf16 + W tiled-transpose) ->
//   gemm8<0> (QKV, persistent: 256 blocks x 3 tiles) -> attn_win (merge-fused) ->
//   gemm8<1> (output proj; blocks >=256 run the attn_weights reduction).
// gemm8: R6-proven 256x256 8-phase counted-vmcnt body (0 conflicts), wrapped
//   in a rep-loop (MODE 0: 3 tiles/block) to amortize dispatch rounds.

#define SEQ   4096
#define NB    8
#define DIM   512
#define NWIN  1024
#define MTOT  (NB*SEQ)   // 32768

typedef __bf16 bf16x8 __attribute__((ext_vector_type(8)));
typedef float  f32x4  __attribute__((ext_vector_type(4)));

__device__ __forceinline__ float b2f(unsigned short u) {
  union { unsigned int i; float f; } z; z.i = ((unsigned int)u) << 16; return z.f;
}
__device__ __forceinline__ unsigned short f2b(float f) {
  __bf16 h = (__bf16)f; return __builtin_bit_cast(unsigned short, h);
}
__device__ __forceinline__ void gload_lds16(const void* g, void* l) {
  __builtin_amdgcn_global_load_lds(
      (__attribute__((address_space(1))) void*)g,
      (__attribute__((address_space(3))) void*)l, 16, 0, 0);
}

#define FENCE() asm volatile("" ::: "memory")
#define BAR()   __builtin_amdgcn_s_barrier()
#define LGK0()  asm volatile("s_waitcnt lgkmcnt(0)" ::: "memory")
#define VMW4()  asm volatile("s_waitcnt vmcnt(4)" ::: "memory")
#define VMW0()  asm volatile("s_waitcnt vmcnt(0)" ::: "memory")

// ---------------- fused convert: x (fp32->bf16) + W transpose (LDS-tiled) ----
__global__ __launch_bounds__(256) void cvt_fused(
    const float* __restrict__ x, const float* __restrict__ W0,
    const float* __restrict__ W1, const float* __restrict__ W2,
    const float* __restrict__ W3,
    unsigned short* __restrict__ xb, unsigned short* __restrict__ Wt) {
  if (blockIdx.x < 2048) {
    const int n8 = MTOT * DIM / 8;
    const int stride = 2048 * 256;
    for (int i = blockIdx.x * 256 + threadIdx.x; i < n8; i += stride) {
      const float4 a = *(const float4*)(x + (size_t)i * 8);
      const float4 c = *(const float4*)(x + (size_t)i * 8 + 4);
      unsigned short u[8] = {f2b(a.x), f2b(a.y), f2b(a.z), f2b(a.w),
                             f2b(c.x), f2b(c.y), f2b(c.z), f2b(c.w)};
      *(int4*)(xb + (size_t)i * 8) = *(const int4*)u;
    }
  } else {
    __shared__ float tile[64][65];          // +1 pad: conflict-free transpose
    const int bb = blockIdx.x - 2048;       // 0..255
    const int w = bb >> 6;                  // matrix 0..3
    const int tr = (bb & 63) >> 3, tc = bb & 7;
    const float* W = (w == 0) ? W0 : (w == 1) ? W1 : (w == 2) ? W2 : W3;
    const int c = threadIdx.x & 63, r4 = threadIdx.x >> 6;
#pragma unroll
    for (int i = 0; i < 16; ++i) {
      int r = r4 + i * 4;
      tile[r][c] = W[(size_t)(tr * 64 + r) * 512 + tc * 64 + c];  // coalesced read
    }
    __syncthreads();
    const int kk = threadIdx.x & 63, n4 = threadIdx.x >> 6;
#pragma unroll
    for (int i = 0; i < 16; ++i) {
      int nn = n4 + i * 4;
      Wt[((size_t)w << 18) + (size_t)(tc * 64 + nn) * 512 + tr * 64 + kk] =
          f2b(tile[kk][nn]);
    }
  }
}

// ---------------- 256x256 8-phase GEMM (persistent) ----------------
// MODE 0: C[32768 x 1536] = A @ Wt[0..3*512)^T + bias, bf16 out; 3 tiles/block
// MODE 1: C[32768 x 512]  = A @ Wo^T, fp32 out with count scaling; 1 tile/block;
//         blocks >= 256 instead run the attn_weights mean-reduction.
// stage index h: K-tile = h>>2, slot = (h+2)&3 (0=A-lo,1=A-hi,2=B-lo,3=B-hi).
__device__ __forceinline__ void stage_part(int h, const unsigned short* pa, const unsigned short* pb,
    int r0s, int c0s, int r1s, int c1s, char* ldsb, int wid) {
  int kt = h >> 2, slot = (h + 2) & 3;
  int buf = kt & 1, ab = slot >> 1, half = slot & 1;
  const unsigned short* src = ab ? pb : pa;
  int rb = half << 7;
  int kc = kt << 6;
  char* d = ldsb + buf * 65536 + ab * 32768 + half * 16384 + wid * 1024;
  gload_lds16(src + (size_t)(rb + r0s) * 512 + kc + c0s, d);
  gload_lds16(src + (size_t)(rb + r1s) * 512 + kc + c1s, d + 8192);
}

#define LDSB(off) (*(const bf16x8*)(ldsb + (off)))

#define RA4(BUF, HALF) { \
  _Pragma("unroll") for (int mf2 = 0; mf2 < 4; ++mf2) { \
    _Pragma("unroll") for (int ks = 0; ks < 2; ++ks) \
      a[mf2][ks] = LDSB(aS[BUF][ks] + (HALF) * 8192 + mf2 * 2048); } }

#define RB2(BUF, QN) { \
  _Pragma("unroll") for (int nf2 = 0; nf2 < 2; ++nf2) { \
    _Pragma("unroll") for (int ks = 0; ks < 2; ++ks) \
      b[(QN)*2+nf2][ks] = LDSB(bS[BUF][ks] + (QN) * 4096 + nf2 * 2048); } }

#define MMQ(QM, QN) { \
  _Pragma("unroll") for (int ks = 0; ks < 2; ++ks) \
  _Pragma("unroll") for (int mf2 = 0; mf2 < 4; ++mf2) \
  _Pragma("unroll") for (int nf2 = 0; nf2 < 2; ++nf2) \
    acc[(QM)*4+mf2][(QN)*2+nf2] = __builtin_amdgcn_mfma_f32_16x16x32_bf16( \
      a[mf2][ks], b[(QN)*2+nf2][ks], acc[(QM)*4+mf2][(QN)*2+nf2], 0, 0, 0); }

template<int MODE>
__global__ __launch_bounds__(512, 2) void gemm8(
    const unsigned short* __restrict__ A, const unsigned short* __restrict__ Bw,
    const float* __restrict__ b0, const float* __restrict__ b1, const float* __restrict__ b2,
    unsigned short* __restrict__ o0, unsigned short* __restrict__ o1, unsigned short* __restrict__ o2,
    float* __restrict__ fout,
    const float* __restrict__ abuf, float* __restrict__ aout) {
  __shared__ unsigned short lds_[65536];   // 128 KiB
  char* ldsb = (char*)lds_;

  if constexpr (MODE == 1) {
    // ---- attn_weights reduction blocks (blockIdx >= 256): proven R10 body ----
    if (blockIdx.x >= 256) {
      if (threadIdx.x < 256) {               // waves 4..7 exit; barrier is wave-aware
        float* sm = (float*)lds_;            // [256][25] = 25 KiB
        int bh = blockIdx.x - 256;           // 0..63 = b*8+h
        int b = bh >> 3, h = bh & 7;
        int t = threadIdx.x;
        float loc[25];
#pragma unroll
        for (int j = 0; j < 25; ++j) loc[j] = 0.f;
        for (int n = t; n < NWIN; n += 256) {
          const float* p = abuf + ((size_t)(b * NWIN + n) * 8 + h) * 25;
#pragma unroll
          for (int j = 0; j < 25; ++j) loc[j] += p[j];
        }
#pragma unroll
        for (int j = 0; j < 25; ++j) sm[t * 25 + j] = loc[j];
        __syncthreads();
        for (int off = 128; off > 0; off >>= 1) {
          if (t < off)
#pragma unroll
            for (int j = 0; j < 25; ++j) sm[t * 25 + j] += sm[(t + off) * 25 + j];
          __syncthreads();
        }
        if (t < 25) aout[bh * 25 + t] = sm[t] * (1.0f / 1024.0f);
      }
      return;
    }
  }

  // 256 GEMM blocks in both modes -> shared XCD mapping (cpx = 32)
  constexpr int REPS = (MODE == 0) ? 3 : 1;
  constexpr int NTN  = (MODE == 0) ? 6 : 2;
  const int g = blockIdx.x;
  const int sw0 = (g & 7) * 32 + (g >> 3);

  const int tid = threadIdx.x;
  const int lane = tid & 63;
  const int wid = tid >> 6;
  const int wr = wid >> 2, wc = wid & 3;
  const int cl16 = lane & 15, hi = lane >> 4;
  const int hi16 = hi * 16;
  const int sxor = (cl16 & 14) << 3;

  int o0_ = tid * 16;
  int o1_ = 8192 + tid * 16;
  int l0 = o0_ ^ (((o0_ >> 8) & 7) << 4);
  int l1 = o1_ ^ (((o1_ >> 8) & 7) << 4);
  const int r0s = l0 >> 7, c0s = (l0 & 127) >> 1;
  const int r1s = l1 >> 7, c1s = (l1 & 127) >> 1;

  int aS[2][2], bS[2][2];
#pragma unroll
  for (int bu = 0; bu < 2; ++bu)
#pragma unroll
    for (int ks = 0; ks < 2; ++ks) {
      aS[bu][ks] = bu * 65536 + ((wr * 16384 + cl16 * 128 + ks * 64 + hi16) ^ sxor);
      bS[bu][ks] = bu * 65536 + 32768 + (((wc >> 1) * 16384 + (wc & 1) * 8192 + cl16 * 128 + ks * 64 + hi16) ^ sxor);
    }

  for (int rep = 0; rep < REPS; ++rep) {
    const int sw = sw0 + rep * 256;
    const int ntile = sw % NTN, mtile = sw / NTN;
    const int m0 = mtile * 256, n0g = ntile * 256;
    const unsigned short* pa = A + (size_t)m0 * 512;
    const unsigned short* pb = Bw + (size_t)n0g * 512;

    f32x4 acc[8][4] = {};
    bf16x8 a[4][2], b[4][2];

#define STG(H) stage_part((H), pa, pb, r0s, c0s, r1s, c1s, ldsb, wid)

    STG(0); STG(1); STG(2); STG(3); STG(4); STG(5);
    VMW4();
    FENCE(); BAR();

#pragma unroll
    for (int it = 0; it < 4; ++it) {
      const int hb = 8 * it;
      RA4(0, 0); RB2(0, 0);
      STG(hb + 6);
      FENCE(); BAR();
      __builtin_amdgcn_s_setprio(1); MMQ(0, 0); __builtin_amdgcn_s_setprio(0);
      FENCE(); BAR();
      RB2(0, 1);
      if (hb + 7 < 32) STG(hb + 7);
      FENCE(); BAR();
      __builtin_amdgcn_s_setprio(1); MMQ(0, 1); __builtin_amdgcn_s_setprio(0);
      FENCE(); BAR();
      RA4(0, 1);
      if (it < 3) STG(hb + 8);
      FENCE(); BAR();
      __builtin_amdgcn_s_setprio(1); MMQ(1, 1); __builtin_amdgcn_s_setprio(0);
      FENCE(); BAR();
      if (it < 3) STG(hb + 9);
      FENCE(); BAR();
      __builtin_amdgcn_s_setprio(1); MMQ(1, 0); __builtin_amdgcn_s_setprio(0);
      if (it < 3) { VMW4(); } else { VMW0(); }
      FENCE(); BAR();
      RA4(1, 0); RB2(1, 0);
      if (it < 3) STG(hb + 10);
      FENCE(); BAR();
      __builtin_amdgcn_s_setprio(1); MMQ(0, 0); __builtin_amdgcn_s_setprio(0);
      FENCE(); BAR();
      RB2(1, 1);
      if (it < 3) STG(hb + 11);
      FENCE(); BAR();
      __builtin_amdgcn_s_setprio(1); MMQ(0, 1); __builtin_amdgcn_s_setprio(0);
      FENCE(); BAR();
      RA4(1, 1);
      if (it < 3) STG(hb + 12);
      FENCE(); BAR();
      __builtin_amdgcn_s_setprio(1); MMQ(1, 1); __builtin_amdgcn_s_setprio(0);
      FENCE(); BAR();
      if (it < 3) STG(hb + 13);
      FENCE(); BAR();
      __builtin_amdgcn_s_setprio(1); MMQ(1, 0); __builtin_amdgcn_s_setprio(0);
      if (it < 3) { VMW4(); }
      FENCE(); BAR();
    }

    if constexpr (MODE == 0) {
      const int sel = n0g >> 9;
      const float* bias = (sel == 0) ? b0 : (sel == 1) ? b1 : b2;
      unsigned short* C = (sel == 0) ? o0 : (sel == 1) ? o1 : o2;
      const int lcb = (n0g & 511) + wc * 64;
      unsigned short* wlds = lds_ + wid * 8192;
#pragma unroll
      for (int mf = 0; mf < 8; ++mf)
#pragma unroll
        for (int nf = 0; nf < 4; ++nf) {
          float bv_ = bias[lcb + nf * 16 + cl16];
#pragma unroll
          for (int r = 0; r < 4; ++r) {
            int w = (mf * 16 + hi * 4 + r) * 64 + nf * 16 + cl16;
            wlds[w ^ (((w >> 7) & 7) << 3)] = f2b(acc[mf][nf][r] + bv_);
          }
        }
      LGK0();
#pragma unroll
      for (int itr = 0; itr < 16; ++itr) {
        int f = itr * 512 + lane * 8;
        int row = f >> 6, col = f & 63;
        int4 v = *(const int4*)&wlds[f ^ (((f >> 7) & 7) << 3)];
        *(int4*)(C + (size_t)(m0 + wr * 128 + row) * 512 + lcb + col) = v;
      }
      if (rep < REPS - 1) { LGK0(); FENCE(); BAR(); }  // LDS safe before restage
    } else {
#pragma unroll
      for (int nf = 0; nf < 4; ++nf) {
        int ncol = n0g + wc * 64 + nf * 16 + cl16;
        float bv_ = b0[ncol];
#pragma unroll
        for (int mf = 0; mf < 8; ++mf) {
          int rbase = m0 + wr * 128 + mf * 16 + hi * 4;
#pragma unroll
          for (int r = 0; r < 4; ++r) {
            int row = rbase + r;
            int s = row & (SEQ - 1);
            float cnt = ((s & 3) == 0 && s > 0) ? 2.0f : 1.0f;
            fout[(size_t)row * 512 + ncol] = (acc[mf][nf][r] + cnt * bv_) / (cnt + 1e-6f);
          }
        }
      }
    }
  }
}

// ---------------- windowed attention, merge-fused (R10-proven) ----------------
__global__ __launch_bounds__(256) void attn_win(
    const unsigned short* __restrict__ Qb, const unsigned short* __restrict__ Kb,
    const unsigned short* __restrict__ Vb,
    const float* __restrict__ bq, const float* __restrict__ bk, const float* __restrict__ bv,
    unsigned short* __restrict__ yb, float* __restrict__ abuf) {
  const int g = blockIdx.x;
  const int swg = (g & 7) * 256 + (g >> 3);   // XCD-chunked: neighbors share L2
  const int gw = swg * 4 + (threadIdx.x >> 6);
  const int b = gw >> 10, n = gw & (NWIN - 1);
  const int lane = threadIdx.x & 63;
  const int h = lane >> 3, e = lane & 7;
  const int dbase = h * 64 + e * 8;
  const size_t rowbase = (size_t)b * SEQ;

  // ---- prev-window row 4 (position 4n) ----
  float o4[8];
#pragma unroll
  for (int d = 0; d < 8; ++d) o4[d] = 0.f;
  if (n > 0) {
    float q0[8];
    {
      int4 qv = *(const int4*)(Qb + (rowbase + 4 * n) * DIM + dbase);
      const unsigned short* qp = (const unsigned short*)&qv;
#pragma unroll
      for (int d = 0; d < 8; ++d) q0[d] = b2f(qp[d]);
    }
    float sc[5];
#pragma unroll
    for (int j = 0; j < 5; ++j) {
      int p = 4 * n - 4 + j;
      int4 kv = *(const int4*)(Kb + (rowbase + p) * DIM + dbase);
      const unsigned short* kp = (const unsigned short*)&kv;
      float t = 0.f;
#pragma unroll
      for (int d = 0; d < 8; ++d) t += q0[d] * b2f(kp[d]);
      t += __shfl_xor(t, 1);
      t += __shfl_xor(t, 2);
      t += __shfl_xor(t, 4);
      sc[j] = t * 0.125f;
    }
    float mx = sc[0];
#pragma unroll
    for (int j = 1; j < 5; ++j) mx = fmaxf(mx, sc[j]);
    float ex[5], sum = 0.f;
#pragma unroll
    for (int j = 0; j < 5; ++j) { ex[j] = __expf(sc[j] - mx); sum += ex[j]; }
    float inv = 1.0f / sum;
#pragma unroll
    for (int j = 0; j < 5; ++j) {
      int p = 4 * n - 4 + j;
      int4 vv = *(const int4*)(Vb + (rowbase + p) * DIM + dbase);
      const unsigned short* vp = (const unsigned short*)&vv;
      float wj = ex[j] * inv;
#pragma unroll
      for (int d = 0; d < 8; ++d) o4[d] += wj * b2f(vp[d]);
    }
  }

  // ---- own window ----
  float kf[5][8], vf[5][8];
#pragma unroll
  for (int j = 0; j < 5; ++j) {
    int p = 4 * n + j;
    if (p < SEQ) {
      int4 kv = *(const int4*)(Kb + (rowbase + p) * DIM + dbase);
      int4 vv = *(const int4*)(Vb + (rowbase + p) * DIM + dbase);
      const unsigned short* kp = (const unsigned short*)&kv;
      const unsigned short* vp = (const unsigned short*)&vv;
#pragma unroll
      for (int d = 0; d < 8; ++d) { kf[j][d] = b2f(kp[d]); vf[j][d] = b2f(vp[d]); }
    } else {  // zero-pad row (window 1023 only): k = bk, v = bv
#pragma unroll
      for (int d = 0; d < 8; ++d) { kf[j][d] = bk[dbase + d]; vf[j][d] = bv[dbase + d]; }
    }
  }
  float pm[5][5];
#pragma unroll
  for (int i = 0; i < 5; ++i) {
    int p = 4 * n + i;
    float qf[8];
    if (p < SEQ) {
      int4 qv = *(const int4*)(Qb + (rowbase + p) * DIM + dbase);
      const unsigned short* qp = (const unsigned short*)&qv;
#pragma unroll
      for (int d = 0; d < 8; ++d) qf[d] = b2f(qp[d]);
    } else {
#pragma unroll
      for (int d = 0; d < 8; ++d) qf[d] = bq[dbase + d];
    }
    float sr[5];
#pragma unroll
    for (int j = 0; j < 5; ++j) {
      float t = 0.f;
#pragma unroll
      for (int d = 0; d < 8; ++d) t += qf[d] * kf[j][d];
      t += __shfl_xor(t, 1);
      t += __shfl_xor(t, 2);
      t += __shfl_xor(t, 4);
      sr[j] = t * 0.125f;
    }
    float mx = sr[0];
#pragma unroll
    for (int j = 1; j < 5; ++j) mx = fmaxf(mx, sr[j]);
    float ex[5], sum = 0.f;
#pragma unroll
    for (int j = 0; j < 5; ++j) { ex[j] = __expf(sr[j] - mx); sum += ex[j]; }
    float inv = 1.0f / sum;
#pragma unroll
    for (int j = 0; j < 5; ++j) pm[i][j] = ex[j] * inv;
    if (i < 4) {   // rows 0..3 are this block's output rows; row 0 gets merge
      float o[8];
#pragma unroll
      for (int d = 0; d < 8; ++d) o[d] = (i == 0) ? o4[d] : 0.f;
#pragma unroll
      for (int j = 0; j < 5; ++j)
#pragma unroll
        for (int d = 0; d < 8; ++d) o[d] += pm[i][j] * vf[j][d];
      unsigned short u[8];
#pragma unroll
      for (int d = 0; d < 8; ++d) u[d] = f2b(o[d]);
      *(int4*)(yb + (rowbase + p) * DIM + dbase) = *(const int4*)u;
    }
  }
  float* ap = abuf + ((size_t)(b * NWIN + n) * 8 + h) * 25;
  if (e == 0) {
#pragma unroll
    for (int i2 = 0; i2 < 5; ++i2)
#pragma unroll
      for (int j2 = 0; j2 < 5; ++j2) ap[i2 * 5 + j2] = pm[i2][j2];
  }
}

extern "C" void kernel_launch(void* const* d_in, const int* in_sizes, int n_in,
                              void* d_out, int out_size, void* d_ws, size_t ws_size,
                              hipStream_t stream) {
  const float* x  = (const float*)d_in[0];
  const float* Wq = (const float*)d_in[1];
  const float* bq = (const float*)d_in[2];
  const float* Wk = (const float*)d_in[3];
  const float* bk = (const float*)d_in[4];
  const float* Wv = (const float*)d_in[5];
  const float* bv = (const float*)d_in[6];
  const float* Wo = (const float*)d_in[7];
  const float* bo = (const float*)d_in[8];
  float* out = (float*)d_out;

  char* ws = (char*)d_ws;
  unsigned short* xb   = (unsigned short*)(ws);              // 32 MiB (bf16 x / later y)
  unsigned short* yb   = xb;                                 // alias (xb dead after QKV GEMM)
  unsigned short* Qb   = (unsigned short*)(ws + 33554432);
  unsigned short* Kb   = (unsigned short*)(ws + 67108864);
  unsigned short* Vb   = (unsigned short*)(ws + 100663296);
  float*          abuf = (float*)(ws + 142606336);
  unsigned short* Wt   = (unsigned short*)(ws + 149159936);  // 2 MiB: [Wq^T|Wk^T|Wv^T|Wo^T] bf16
  (void)ws_size; (void)in_sizes; (void)n_in; (void)out_size;

  cvt_fused<<<2304, 256, 0, stream>>>(x, Wq, Wk, Wv, Wo, xb, Wt);
  gemm8<0><<<256, 512, 0, stream>>>(xb, Wt, bq, bk, bv, Qb, Kb, Vb, nullptr,
                                    nullptr, nullptr);
  attn_win<<<2048, 256, 0, stream>>>(Qb, Kb, Vb, bq, bk, bv, yb, abuf);
  gemm8<1><<<320, 512, 0, stream>>>(yb, Wt + 3 * (DIM * DIM), bo, nullptr, nullptr,
                                    nullptr, nullptr, nullptr, out,
                                    abuf, out + (size_t)MTOT * DIM);
}

// Round 15
// 145.681 us; speedup vs baseline: 1.6819x; 1.6819x over previous
//
#include <hip/hip_runtime.h>
#include <hip/hip_bf16.h>

// LocalAttention: B=8, S=4096, D=512, H=8, hd=64, WINDOW=5, STRIDE=4, nw=1024
// Pipeline (4 launches): cvt_fused (x->bf16 + W tiled-transpose) ->
//   gemm8<0> (QKV, N=1536) -> attn_win (merge-fused) ->
//   gemm8<1> (output proj; blocks >=256 run the attn_weights reduction).
// gemm8: R6-proven 256x256 8-phase counted-vmcnt kernel (804 TF, 0 conflicts).
// R11/R13 configuration: best measured total (145.7 / 147.1 us). R14's
// persistent-block rep-loop regressed (VGPR spill: WRITE_SIZE 167 MB).

#define SEQ   4096
#define NB    8
#define DIM   512
#define NWIN  1024
#define MTOT  (NB*SEQ)   // 32768

typedef __bf16 bf16x8 __attribute__((ext_vector_type(8)));
typedef float  f32x4  __attribute__((ext_vector_type(4)));

__device__ __forceinline__ float b2f(unsigned short u) {
  union { unsigned int i; float f; } z; z.i = ((unsigned int)u) << 16; return z.f;
}
__device__ __forceinline__ unsigned short f2b(float f) {
  __bf16 h = (__bf16)f; return __builtin_bit_cast(unsigned short, h);
}
__device__ __forceinline__ void gload_lds16(const void* g, void* l) {
  __builtin_amdgcn_global_load_lds(
      (__attribute__((address_space(1))) void*)g,
      (__attribute__((address_space(3))) void*)l, 16, 0, 0);
}

#define FENCE() asm volatile("" ::: "memory")
#define BAR()   __builtin_amdgcn_s_barrier()
#define LGK0()  asm volatile("s_waitcnt lgkmcnt(0)" ::: "memory")
#define VMW4()  asm volatile("s_waitcnt vmcnt(4)" ::: "memory")
#define VMW0()  asm volatile("s_waitcnt vmcnt(0)" ::: "memory")

// ---------------- fused convert: x (fp32->bf16) + W transpose (LDS-tiled) ----
// blocks [0,2048): x grid-stride; blocks [2048,2304): one 64x64 W tile each.
__global__ __launch_bounds__(256) void cvt_fused(
    const float* __restrict__ x, const float* __restrict__ W0,
    const float* __restrict__ W1, const float* __restrict__ W2,
    const float* __restrict__ W3,
    unsigned short* __restrict__ xb, unsigned short* __restrict__ Wt) {
  if (blockIdx.x < 2048) {
    const int n8 = MTOT * DIM / 8;
    const int stride = 2048 * 256;
    for (int i = blockIdx.x * 256 + threadIdx.x; i < n8; i += stride) {
      const float4 a = *(const float4*)(x + (size_t)i * 8);
      const float4 c = *(const float4*)(x + (size_t)i * 8 + 4);
      unsigned short u[8] = {f2b(a.x), f2b(a.y), f2b(a.z), f2b(a.w),
                             f2b(c.x), f2b(c.y), f2b(c.z), f2b(c.w)};
      *(int4*)(xb + (size_t)i * 8) = *(const int4*)u;
    }
  } else {
    __shared__ float tile[64][65];          // +1 pad: conflict-free transpose
    const int bb = blockIdx.x - 2048;       // 0..255
    const int w = bb >> 6;                  // matrix 0..3
    const int tr = (bb & 63) >> 3, tc = bb & 7;
    const float* W = (w == 0) ? W0 : (w == 1) ? W1 : (w == 2) ? W2 : W3;
    const int c = threadIdx.x & 63, r4 = threadIdx.x >> 6;
#pragma unroll
    for (int i = 0; i < 16; ++i) {
      int r = r4 + i * 4;
      tile[r][c] = W[(size_t)(tr * 64 + r) * 512 + tc * 64 + c];  // coalesced read
    }
    __syncthreads();
    const int kk = threadIdx.x & 63, n4 = threadIdx.x >> 6;
#pragma unroll
    for (int i = 0; i < 16; ++i) {
      int nn = n4 + i * 4;
      Wt[((size_t)w << 18) + (size_t)(tc * 64 + nn) * 512 + tr * 64 + kk] =
          f2b(tile[kk][nn]);
    }
  }
}

// ---------------- 256x256 8-phase GEMM (R6-proven, unchanged) ----------------
// MODE 0: C[32768 x 1536] = A @ Wt[0..3*512)^T + bias, bf16 out routed to Q/K/V
// MODE 1: C[32768 x 512]  = A @ Wo^T, fp32 out with count scaling;
//         blocks >= 256 instead run the attn_weights mean-reduction.
// stage index h: K-tile = h>>2, slot = (h+2)&3 (0=A-lo,1=A-hi,2=B-lo,3=B-hi).
__device__ __forceinline__ void stage_part(int h, const unsigned short* pa, const unsigned short* pb,
    int r0s, int c0s, int r1s, int c1s, char* ldsb, int wid) {
  int kt = h >> 2, slot = (h + 2) & 3;
  int buf = kt & 1, ab = slot >> 1, half = slot & 1;
  const unsigned short* src = ab ? pb : pa;
  int rb = half << 7;
  int kc = kt << 6;
  char* d = ldsb + buf * 65536 + ab * 32768 + half * 16384 + wid * 1024;
  gload_lds16(src + (size_t)(rb + r0s) * 512 + kc + c0s, d);
  gload_lds16(src + (size_t)(rb + r1s) * 512 + kc + c1s, d + 8192);
}

#define LDSB(off) (*(const bf16x8*)(ldsb + (off)))

#define RA4(BUF, HALF) { \
  _Pragma("unroll") for (int mf2 = 0; mf2 < 4; ++mf2) { \
    _Pragma("unroll") for (int ks = 0; ks < 2; ++ks) \
      a[mf2][ks] = LDSB(aS[BUF][ks] + (HALF) * 8192 + mf2 * 2048); } }

#define RB2(BUF, QN) { \
  _Pragma("unroll") for (int nf2 = 0; nf2 < 2; ++nf2) { \
    _Pragma("unroll") for (int ks = 0; ks < 2; ++ks) \
      b[(QN)*2+nf2][ks] = LDSB(bS[BUF][ks] + (QN) * 4096 + nf2 * 2048); } }

#define MMQ(QM, QN) { \
  _Pragma("unroll") for (int ks = 0; ks < 2; ++ks) \
  _Pragma("unroll") for (int mf2 = 0; mf2 < 4; ++mf2) \
  _Pragma("unroll") for (int nf2 = 0; nf2 < 2; ++nf2) \
    acc[(QM)*4+mf2][(QN)*2+nf2] = __builtin_amdgcn_mfma_f32_16x16x32_bf16( \
      a[mf2][ks], b[(QN)*2+nf2][ks], acc[(QM)*4+mf2][(QN)*2+nf2], 0, 0, 0); }

template<int MODE>
__global__ __launch_bounds__(512, 2) void gemm8(
    const unsigned short* __restrict__ A, const unsigned short* __restrict__ Bw,
    const float* __restrict__ b0, const float* __restrict__ b1, const float* __restrict__ b2,
    unsigned short* __restrict__ o0, unsigned short* __restrict__ o1, unsigned short* __restrict__ o2,
    float* __restrict__ fout,
    const float* __restrict__ abuf, float* __restrict__ aout) {
  __shared__ unsigned short lds_[65536];   // 128 KiB
  char* ldsb = (char*)lds_;

  if constexpr (MODE == 1) {
    // ---- attn_weights reduction blocks (blockIdx >= 256): proven R10 body ----
    if (blockIdx.x >= 256) {
      if (threadIdx.x < 256) {               // waves 4..7 exit; barrier is wave-aware
        float* sm = (float*)lds_;            // [256][25] = 25 KiB (co-resident ok)
        int bh = blockIdx.x - 256;           // 0..63 = b*8+h
        int b = bh >> 3, h = bh & 7;
        int t = threadIdx.x;
        float loc[25];
#pragma unroll
        for (int j = 0; j < 25; ++j) loc[j] = 0.f;
        for (int n = t; n < NWIN; n += 256) {
          const float* p = abuf + ((size_t)(b * NWIN + n) * 8 + h) * 25;
#pragma unroll
          for (int j = 0; j < 25; ++j) loc[j] += p[j];
        }
#pragma unroll
        for (int j = 0; j < 25; ++j) sm[t * 25 + j] = loc[j];
        __syncthreads();
        for (int off = 128; off > 0; off >>= 1) {
          if (t < off)
#pragma unroll
            for (int j = 0; j < 25; ++j) sm[t * 25 + j] += sm[(t + off) * 25 + j];
          __syncthreads();
        }
        if (t < 25) aout[bh * 25 + t] = sm[t] * (1.0f / 1024.0f);
      }
      return;
    }
  }

  // XCD-aware swizzle over the GEMM blocks only (grid constants hardcoded)
  constexpr int nwg = (MODE == 0) ? 768 : 256;
  constexpr int cpx = nwg >> 3;
  const int g = blockIdx.x;
  const int sw = (g & 7) * cpx + (g >> 3);
  constexpr int NTN = (MODE == 0) ? 6 : 2;
  const int ntile = sw % NTN, mtile = sw / NTN;
  const int m0 = mtile * 256, n0g = ntile * 256;

  const int tid = threadIdx.x;
  const int lane = tid & 63;
  const int wid = tid >> 6;
  const int wr = wid >> 2, wc = wid & 3;
  const int cl16 = lane & 15, hi = lane >> 4;
  const int hi16 = hi * 16;
  const int sxor = (cl16 & 14) << 3;

  int o0_ = tid * 16;
  int o1_ = 8192 + tid * 16;
  int l0 = o0_ ^ (((o0_ >> 8) & 7) << 4);
  int l1 = o1_ ^ (((o1_ >> 8) & 7) << 4);
  const int r0s = l0 >> 7, c0s = (l0 & 127) >> 1;
  const int r1s = l1 >> 7, c1s = (l1 & 127) >> 1;

  const unsigned short* pa = A + (size_t)m0 * 512;
  const unsigned short* pb = Bw + (size_t)n0g * 512;

  int aS[2][2], bS[2][2];
#pragma unroll
  for (int bu = 0; bu < 2; ++bu)
#pragma unroll
    for (int ks = 0; ks < 2; ++ks) {
      aS[bu][ks] = bu * 65536 + ((wr * 16384 + cl16 * 128 + ks * 64 + hi16) ^ sxor);
      bS[bu][ks] = bu * 65536 + 32768 + (((wc >> 1) * 16384 + (wc & 1) * 8192 + cl16 * 128 + ks * 64 + hi16) ^ sxor);
    }

  f32x4 acc[8][4] = {};
  bf16x8 a[4][2], b[4][2];

#define STG(H) stage_part((H), pa, pb, r0s, c0s, r1s, c1s, ldsb, wid)

  STG(0); STG(1); STG(2); STG(3); STG(4); STG(5);
  VMW4();
  FENCE(); BAR();

#pragma unroll
  for (int it = 0; it < 4; ++it) {
    const int hb = 8 * it;
    RA4(0, 0); RB2(0, 0);
    STG(hb + 6);
    FENCE(); BAR();
    __builtin_amdgcn_s_setprio(1); MMQ(0, 0); __builtin_amdgcn_s_setprio(0);
    FENCE(); BAR();
    RB2(0, 1);
    if (hb + 7 < 32) STG(hb + 7);
    FENCE(); BAR();
    __builtin_amdgcn_s_setprio(1); MMQ(0, 1); __builtin_amdgcn_s_setprio(0);
    FENCE(); BAR();
    RA4(0, 1);
    if (it < 3) STG(hb + 8);
    FENCE(); BAR();
    __builtin_amdgcn_s_setprio(1); MMQ(1, 1); __builtin_amdgcn_s_setprio(0);
    FENCE(); BAR();
    if (it < 3) STG(hb + 9);
    FENCE(); BAR();
    __builtin_amdgcn_s_setprio(1); MMQ(1, 0); __builtin_amdgcn_s_setprio(0);
    if (it < 3) { VMW4(); } else { VMW0(); }
    FENCE(); BAR();
    RA4(1, 0); RB2(1, 0);
    if (it < 3) STG(hb + 10);
    FENCE(); BAR();
    __builtin_amdgcn_s_setprio(1); MMQ(0, 0); __builtin_amdgcn_s_setprio(0);
    FENCE(); BAR();
    RB2(1, 1);
    if (it < 3) STG(hb + 11);
    FENCE(); BAR();
    __builtin_amdgcn_s_setprio(1); MMQ(0, 1); __builtin_amdgcn_s_setprio(0);
    FENCE(); BAR();
    RA4(1, 1);
    if (it < 3) STG(hb + 12);
    FENCE(); BAR();
    __builtin_amdgcn_s_setprio(1); MMQ(1, 1); __builtin_amdgcn_s_setprio(0);
    FENCE(); BAR();
    if (it < 3) STG(hb + 13);
    FENCE(); BAR();
    __builtin_amdgcn_s_setprio(1); MMQ(1, 0); __builtin_amdgcn_s_setprio(0);
    if (it < 3) { VMW4(); }
    FENCE(); BAR();
  }

  if constexpr (MODE == 0) {
    const int sel = n0g >> 9;
    const float* bias = (sel == 0) ? b0 : (sel == 1) ? b1 : b2;
    unsigned short* C = (sel == 0) ? o0 : (sel == 1) ? o1 : o2;
    const int lcb = (n0g & 511) + wc * 64;
    unsigned short* wlds = lds_ + wid * 8192;
#pragma unroll
    for (int mf = 0; mf < 8; ++mf)
#pragma unroll
      for (int nf = 0; nf < 4; ++nf) {
        float bv_ = bias[lcb + nf * 16 + cl16];
#pragma unroll
        for (int r = 0; r < 4; ++r) {
          int w = (mf * 16 + hi * 4 + r) * 64 + nf * 16 + cl16;
          wlds[w ^ (((w >> 7) & 7) << 3)] = f2b(acc[mf][nf][r] + bv_);
        }
      }
    LGK0();
#pragma unroll
    for (int itr = 0; itr < 16; ++itr) {
      int f = itr * 512 + lane * 8;
      int row = f >> 6, col = f & 63;
      int4 v = *(const int4*)&wlds[f ^ (((f >> 7) & 7) << 3)];
      *(int4*)(C + (size_t)(m0 + wr * 128 + row) * 512 + lcb + col) = v;
    }
  } else {
#pragma unroll
    for (int nf = 0; nf < 4; ++nf) {
      int ncol = n0g + wc * 64 + nf * 16 + cl16;
      float bv_ = b0[ncol];
#pragma unroll
      for (int mf = 0; mf < 8; ++mf) {
        int rbase = m0 + wr * 128 + mf * 16 + hi * 4;
#pragma unroll
        for (int r = 0; r < 4; ++r) {
          int row = rbase + r;
          int s = row & (SEQ - 1);
          float cnt = ((s & 3) == 0 && s > 0) ? 2.0f : 1.0f;
          fout[(size_t)row * 512 + ncol] = (acc[mf][nf][r] + cnt * bv_) / (cnt + 1e-6f);
        }
      }
    }
  }
}

// ---------------- windowed attention, merge-fused (R10-proven) ----------------
__global__ __launch_bounds__(256) void attn_win(
    const unsigned short* __restrict__ Qb, const unsigned short* __restrict__ Kb,
    const unsigned short* __restrict__ Vb,
    const float* __restrict__ bq, const float* __restrict__ bk, const float* __restrict__ bv,
    unsigned short* __restrict__ yb, float* __restrict__ abuf) {
  const int g = blockIdx.x;
  const int swg = (g & 7) * 256 + (g >> 3);   // XCD-chunked: neighbors share L2
  const int gw = swg * 4 + (threadIdx.x >> 6);
  const int b = gw >> 10, n = gw & (NWIN - 1);
  const int lane = threadIdx.x & 63;
  const int h = lane >> 3, e = lane & 7;
  const int dbase = h * 64 + e * 8;
  const size_t rowbase = (size_t)b * SEQ;

  // ---- prev-window row 4 (position 4n) ----
  float o4[8];
#pragma unroll
  for (int d = 0; d < 8; ++d) o4[d] = 0.f;
  if (n > 0) {
    float q0[8];
    {
      int4 qv = *(const int4*)(Qb + (rowbase + 4 * n) * DIM + dbase);
      const unsigned short* qp = (const unsigned short*)&qv;
#pragma unroll
      for (int d = 0; d < 8; ++d) q0[d] = b2f(qp[d]);
    }
    float sc[5];
#pragma unroll
    for (int j = 0; j < 5; ++j) {
      int p = 4 * n - 4 + j;
      int4 kv = *(const int4*)(Kb + (rowbase + p) * DIM + dbase);
      const unsigned short* kp = (const unsigned short*)&kv;
      float t = 0.f;
#pragma unroll
      for (int d = 0; d < 8; ++d) t += q0[d] * b2f(kp[d]);
      t += __shfl_xor(t, 1);
      t += __shfl_xor(t, 2);
      t += __shfl_xor(t, 4);
      sc[j] = t * 0.125f;
    }
    float mx = sc[0];
#pragma unroll
    for (int j = 1; j < 5; ++j) mx = fmaxf(mx, sc[j]);
    float ex[5], sum = 0.f;
#pragma unroll
    for (int j = 0; j < 5; ++j) { ex[j] = __expf(sc[j] - mx); sum += ex[j]; }
    float inv = 1.0f / sum;
#pragma unroll
    for (int j = 0; j < 5; ++j) {
      int p = 4 * n - 4 + j;
      int4 vv = *(const int4*)(Vb + (rowbase + p) * DIM + dbase);
      const unsigned short* vp = (const unsigned short*)&vv;
      float wj = ex[j] * inv;
#pragma unroll
      for (int d = 0; d < 8; ++d) o4[d] += wj * b2f(vp[d]);
    }
  }

  // ---- own window ----
  float kf[5][8], vf[5][8];
#pragma unroll
  for (int j = 0; j < 5; ++j) {
    int p = 4 * n + j;
    if (p < SEQ) {
      int4 kv = *(const int4*)(Kb + (rowbase + p) * DIM + dbase);
      int4 vv = *(const int4*)(Vb + (rowbase + p) * DIM + dbase);
      const unsigned short* kp = (const unsigned short*)&kv;
      const unsigned short* vp = (const unsigned short*)&vv;
#pragma unroll
      for (int d = 0; d < 8; ++d) { kf[j][d] = b2f(kp[d]); vf[j][d] = b2f(vp[d]); }
    } else {  // zero-pad row (window 1023 only): k = bk, v = bv
#pragma unroll
      for (int d = 0; d < 8; ++d) { kf[j][d] = bk[dbase + d]; vf[j][d] = bv[dbase + d]; }
    }
  }
  float pm[5][5];
#pragma unroll
  for (int i = 0; i < 5; ++i) {
    int p = 4 * n + i;
    float qf[8];
    if (p < SEQ) {
      int4 qv = *(const int4*)(Qb + (rowbase + p) * DIM + dbase);
      const unsigned short* qp = (const unsigned short*)&qv;
#pragma unroll
      for (int d = 0; d < 8; ++d) qf[d] = b2f(qp[d]);
    } else {
#pragma unroll
      for (int d = 0; d < 8; ++d) qf[d] = bq[dbase + d];
    }
    float sr[5];
#pragma unroll
    for (int j = 0; j < 5; ++j) {
      float t = 0.f;
#pragma unroll
      for (int d = 0; d < 8; ++d) t += qf[d] * kf[j][d];
      t += __shfl_xor(t, 1);
      t += __shfl_xor(t, 2);
      t += __shfl_xor(t, 4);
      sr[j] = t * 0.125f;
    }
    float mx = sr[0];
#pragma unroll
    for (int j = 1; j < 5; ++j) mx = fmaxf(mx, sr[j]);
    float ex[5], sum = 0.f;
#pragma unroll
    for (int j = 0; j < 5; ++j) { ex[j] = __expf(sr[j] - mx); sum += ex[j]; }
    float inv = 1.0f / sum;
#pragma unroll
    for (int j = 0; j < 5; ++j) pm[i][j] = ex[j] * inv;
    if (i < 4) {   // rows 0..3 are this block's output rows; row 0 gets merge
      float o[8];
#pragma unroll
      for (int d = 0; d < 8; ++d) o[d] = (i == 0) ? o4[d] : 0.f;
#pragma unroll
      for (int j = 0; j < 5; ++j)
#pragma unroll
        for (int d = 0; d < 8; ++d) o[d] += pm[i][j] * vf[j][d];
      unsigned short u[8];
#pragma unroll
      for (int d = 0; d < 8; ++d) u[d] = f2b(o[d]);
      *(int4*)(yb + (rowbase + p) * DIM + dbase) = *(const int4*)u;
    }
  }
  float* ap = abuf + ((size_t)(b * NWIN + n) * 8 + h) * 25;
  if (e == 0) {
#pragma unroll
    for (int i2 = 0; i2 < 5; ++i2)
#pragma unroll
      for (int j2 = 0; j2 < 5; ++j2) ap[i2 * 5 + j2] = pm[i2][j2];
  }
}

extern "C" void kernel_launch(void* const* d_in, const int* in_sizes, int n_in,
                              void* d_out, int out_size, void* d_ws, size_t ws_size,
                              hipStream_t stream) {
  const float* x  = (const float*)d_in[0];
  const float* Wq = (const float*)d_in[1];
  const float* bq = (const float*)d_in[2];
  const float* Wk = (const float*)d_in[3];
  const float* bk = (const float*)d_in[4];
  const float* Wv = (const float*)d_in[5];
  const float* bv = (const float*)d_in[6];
  const float* Wo = (const float*)d_in[7];
  const float* bo = (const float*)d_in[8];
  float* out = (float*)d_out;

  char* ws = (char*)d_ws;
  unsigned short* xb   = (unsigned short*)(ws);              // 32 MiB (bf16 x / later y)
  unsigned short* yb   = xb;                                 // alias (xb dead after QKV GEMM)
  unsigned short* Qb   = (unsigned short*)(ws + 33554432);
  unsigned short* Kb   = (unsigned short*)(ws + 67108864);
  unsigned short* Vb   = (unsigned short*)(ws + 100663296);
  float*          abuf = (float*)(ws + 142606336);
  unsigned short* Wt   = (unsigned short*)(ws + 149159936);  // 2 MiB: [Wq^T|Wk^T|Wv^T|Wo^T] bf16
  (void)ws_size; (void)in_sizes; (void)n_in; (void)out_size;

  cvt_fused<<<2304, 256, 0, stream>>>(x, Wq, Wk, Wv, Wo, xb, Wt);
  gemm8<0><<<768, 512, 0, stream>>>(xb, Wt, bq, bk, bv, Qb, Kb, Vb, nullptr,
                                    nullptr, nullptr);
  attn_win<<<2048, 256, 0, stream>>>(Qb, Kb, Vb, bq, bk, bv, yb, abuf);
  gemm8<1><<<320, 512, 0, stream>>>(yb, Wt + 3 * (DIM * DIM), bo, nullptr, nullptr,
                                    nullptr, nullptr, nullptr, out,
                                    abuf, out + (size_t)MTOT * DIM);
}